// Round 5
// baseline (2003.245 us; speedup 1.0000x reference)
//
#include <hip/hip_runtime.h>
#include <hip/hip_fp16.h>

#define NN   100000
#define NNP  100096          // 782 * 128, padded row count for hop/GEMM buffers
#define EE   3200000
#define DD   256
#define DOUTC 64
#define LSTR 40              // LDS row stride in halves (80 B, 16B-aligned, 2-way bank alias = free)

#define NBK  782             // buckets of 128 rows (row >> 7); 782*128 = 100096 >= NN
#define PB   512             // partition blocks for scatter
#define CHUNK 6250           // edges per partition block; 512*6250 = EE exactly
#define STATB 512            // col_stats blocks
#define CAP  4736            // fixed bucket capacity: mean 4092 + 10 sigma

typedef _Float16 half8 __attribute__((ext_vector_type(8)));
typedef _Float16 half4 __attribute__((ext_vector_type(4)));
typedef float    f32x4 __attribute__((ext_vector_type(4)));

__device__ inline f32x4 mfma16(half8 a, half8 b, f32x4 c) {
    return __builtin_amdgcn_mfma_f32_16x16x32_f16(a, b, c, 0, 0, 0);
}

// fast tanh: 1 - 2/(e^{2v}+1). v_exp + v_rcp, ~1e-7 abs error (fp16 downstream).
__device__ inline float fast_tanh(float v) {
    float e = __expf(2.0f * v);
    return 1.0f - 2.0f * __builtin_amdgcn_rcpf(e + 1.0f);
}

// ================= Phase A: col_stats (blocks 0..511) || edge scatter (512..1023) ==========
// col_stats: sum/sumsq per column (+ optional x -> hi/lo fp16 split).
// scatter: global-atomic cursor per bucket, fixed-capacity layout ebufP[bkt*CAP + i].
template<bool WSPLIT>
__global__ __launch_bounds__(256) void phaseA_kernel(
        const float* __restrict__ x, float* __restrict__ stats,
        _Float16* __restrict__ xh, _Float16* __restrict__ xl,
        const int* __restrict__ rows, const int* __restrict__ cols,
        const float* __restrict__ vals,
        int* __restrict__ cnt, int2* __restrict__ ebufP) {
    int blk = blockIdx.x;
    int tid = threadIdx.x;
    if (blk < STATB) {
        __shared__ float4 shs[4][64];
        __shared__ float4 shs2[4][64];
        int c4 = tid & 63;          // float4 chunk of the 256-col row
        int rq = tid >> 6;          // wave id 0..3
        float4 s  = make_float4(0.f, 0.f, 0.f, 0.f);
        float4 s2 = make_float4(0.f, 0.f, 0.f, 0.f);
        for (int r = blk * 4 + rq; r < NN; r += STATB * 4) {
            float4 v = *(const float4*)&x[(size_t)r * DD + c4 * 4];
            s.x += v.x; s.y += v.y; s.z += v.z; s.w += v.w;
            s2.x += v.x * v.x; s2.y += v.y * v.y; s2.z += v.z * v.z; s2.w += v.w * v.w;
            if (WSPLIT) {
                half4 hi, lo;
                hi.x = (_Float16)v.x; lo.x = (_Float16)(v.x - (float)hi.x);
                hi.y = (_Float16)v.y; lo.y = (_Float16)(v.y - (float)hi.y);
                hi.z = (_Float16)v.z; lo.z = (_Float16)(v.z - (float)hi.z);
                hi.w = (_Float16)v.w; lo.w = (_Float16)(v.w - (float)hi.w);
                *(half4*)&xh[(size_t)r * DD + c4 * 4] = hi;
                *(half4*)&xl[(size_t)r * DD + c4 * 4] = lo;
            }
        }
        shs[rq][c4] = s;
        shs2[rq][c4] = s2;
        __syncthreads();
        if (rq == 0) {
#pragma unroll
            for (int q = 1; q < 4; ++q) {
                float4 a = shs[q][c4], b = shs2[q][c4];
                s.x += a.x; s.y += a.y; s.z += a.z; s.w += a.w;
                s2.x += b.x; s2.y += b.y; s2.z += b.z; s2.w += b.w;
            }
            atomicAdd(&stats[c4 * 4 + 0], s.x);
            atomicAdd(&stats[c4 * 4 + 1], s.y);
            atomicAdd(&stats[c4 * 4 + 2], s.z);
            atomicAdd(&stats[c4 * 4 + 3], s.w);
            atomicAdd(&stats[DD + c4 * 4 + 0], s2.x);
            atomicAdd(&stats[DD + c4 * 4 + 1], s2.y);
            atomicAdd(&stats[DD + c4 * 4 + 2], s2.z);
            atomicAdd(&stats[DD + c4 * 4 + 3], s2.w);
        }
    } else {
        int pb = blk - STATB;
        int base = pb * CHUNK;
        for (int e = base + tid; e < base + CHUNK; e += 256) {
            int r = __builtin_nontemporal_load(&rows[e]);
            int c = __builtin_nontemporal_load(&cols[e]);
            float v = __builtin_nontemporal_load(&vals[e]);
            int bkt = r >> 7;
            int lr = atomicAdd(&cnt[bkt], 1);
            if (lr < CAP)
                ebufP[(size_t)bkt * CAP + lr] =
                    make_int2(c | ((r & 127) << 17), __float_as_int(v));
        }
    }
}

// ================= Phase B: finalize (blocks 0..781) || weight prep (782..1550) =============
// finalize: per-bucket 128-row hist+scan in LDS -> rps/rpe + row-major edgesP
// prep: b2 in [0,DD)=w1, [DD,2DD)=w2, [2DD,3DD)=w3, [3DD]=fold_bias
__global__ __launch_bounds__(256) void phaseB_kernel(
        const int* __restrict__ cnt, const int2* __restrict__ ebufP,
        int* __restrict__ rps, int* __restrict__ rpe, int2* __restrict__ edgesP,
        const float* __restrict__ stats, const float* __restrict__ gamma,
        const float* __restrict__ beta, const float* __restrict__ w_in,
        const float* __restrict__ b_in, const float* __restrict__ w_conv,
        const float* __restrict__ w_out,
        _Float16* __restrict__ wt1h, _Float16* __restrict__ wt1l,
        _Float16* __restrict__ wt2h, _Float16* __restrict__ wt2l,
        _Float16* __restrict__ wt3h, _Float16* __restrict__ wt3l,
        float* __restrict__ bfold) {
    int blk = blockIdx.x;
    int t = threadIdx.x;
    if (blk < NBK) {
        __shared__ int hist[128];
        __shared__ int excl[128];
        __shared__ int cur[128];
        __shared__ int sc[128];
        int b = blk;
        int e0 = b * CAP;
        int n = min(cnt[b], CAP);
        int e1 = e0 + n;
        if (t < 128) { hist[t] = 0; cur[t] = 0; }
        __syncthreads();
        for (int e = e0 + t; e < e1; e += 256)
            atomicAdd(&hist[ebufP[e].x >> 17], 1);
        __syncthreads();
        if (t < 128) sc[t] = hist[t];
        __syncthreads();
        for (int off = 1; off < 128; off <<= 1) {
            int xv = 0;
            if (t < 128 && t >= off) xv = sc[t - off];
            __syncthreads();
            if (t < 128 && t >= off) sc[t] += xv;
            __syncthreads();
        }
        if (t < 128) {
            excl[t] = sc[t] - hist[t];
            int gr = b * 128 + t;
            if (gr < NN) {
                rps[gr] = e0 + excl[t];
                rpe[gr] = e0 + excl[t] + hist[t];
            }
        }
        __syncthreads();
        for (int e = e0 + t; e < e1; e += 256) {
            int2 d = ebufP[e];
            int rl = d.x >> 17;
            int lr = atomicAdd(&cur[rl], 1);
            edgesP[e0 + excl[rl] + lr] = make_int2(d.x & 0x1FFFF, d.y);
        }
    } else {
        int b2 = blk - NBK;
        if (b2 < DD) {                       // w1 (BN-scaled), col k=b2
            float mean = stats[b2] * (1.0f / NN);
            float var  = stats[DD + b2] * (1.0f / NN) - mean * mean;
            float a = gamma[b2] * rsqrtf(var + 1e-5f);
            float v = a * w_in[(size_t)b2 * DD + t];
            _Float16 hi = (_Float16)v;
            _Float16 lo = (_Float16)(v - (float)hi);
            wt1h[(size_t)t * DD + b2] = hi;
            wt1l[(size_t)t * DD + b2] = lo;
        } else if (b2 < 2 * DD) {            // w2, col k=b2-DD
            int k = b2 - DD;
            float v = w_conv[(size_t)k * DD + t];
            _Float16 hi = (_Float16)v;
            _Float16 lo = (_Float16)(v - (float)hi);
            wt2h[(size_t)t * DD + k] = hi;
            wt2l[(size_t)t * DD + k] = lo;
        } else if (b2 < 3 * DD) {            // w3, col k=b2-2DD (only DOUTC outputs)
            int k = b2 - 2 * DD;
            if (t < DOUTC) {
                float v = w_out[(size_t)k * DOUTC + t];
                _Float16 hi = (_Float16)v;
                _Float16 lo = (_Float16)(v - (float)hi);
                wt3h[(size_t)t * DD + k] = hi;
                wt3l[(size_t)t * DD + k] = lo;
            }
        } else {                             // fold_bias
            __shared__ float sb[DD];
            float mean = stats[t] * (1.0f / NN);
            float var  = stats[DD + t] * (1.0f / NN) - mean * mean;
            float a = gamma[t] * rsqrtf(var + 1e-5f);
            sb[t] = beta[t] - mean * a;
            __syncthreads();
            float acc = 0.f;
            for (int j = 0; j < DD; ++j) acc += sb[j] * w_in[j * DD + t];
            bfold[t] = b_in[t] + acc;
        }
    }
}

// ---------------- spmm: inline-asm FORCED 8-deep gather pipeline ----------------
// 1 wave per row; 2 edge slots x 32 feature lanes (one float4 = 8 halves each).
__device__ inline void fma8(float (&acc)[8], float v, const f32x4& xv) {
    const __half2* hp = (const __half2*)&xv;
    float2 f0 = __half22float2(hp[0]);
    float2 f1 = __half22float2(hp[1]);
    float2 f2 = __half22float2(hp[2]);
    float2 f3 = __half22float2(hp[3]);
    acc[0] += v*f0.x; acc[1] += v*f0.y;
    acc[2] += v*f1.x; acc[3] += v*f1.y;
    acc[4] += v*f2.x; acc[5] += v*f2.y;
    acc[6] += v*f3.x; acc[7] += v*f3.y;
}

__global__ __launch_bounds__(256) void spmm_kernel(
        const int* __restrict__ rps, const int* __restrict__ rpe,
        const int2* __restrict__ edges,
        const __half* __restrict__ xin, __half* __restrict__ xout) {
    int tid = threadIdx.x;
    int lane = tid & 63;
    int sub = lane >> 5;         // edge slot 0..1
    int sl = lane & 31;          // feature chunk (8 halves each), 32 = full row
    int r = __builtin_amdgcn_readfirstlane(blockIdx.x * 4 + (tid >> 6));
    int e0 = rps[r], e1 = rpe[r];
    const f32x4* xi = (const f32x4*)xin;   // 32 float4 chunks per row
    const long long* epk = (const long long*)edges;

    float acc[8] = {0.f,0.f,0.f,0.f,0.f,0.f,0.f,0.f};

    int base = e0;
    // main: 16 edges/iter; slot s handles edges [base+8s, base+8s+8).
    // The 8 gathers are emitted as one asm block -> guaranteed 8 loads in flight.
    for (; base + 16 <= e1; base += 16) {
        long long p[8];
#pragma unroll
        for (int i = 0; i < 8; ++i)
            p[i] = __builtin_nontemporal_load(&epk[base + sub * 8 + i]);
        const f32x4* a0 = xi + (size_t)(unsigned int)p[0] * 32 + sl;
        const f32x4* a1 = xi + (size_t)(unsigned int)p[1] * 32 + sl;
        const f32x4* a2 = xi + (size_t)(unsigned int)p[2] * 32 + sl;
        const f32x4* a3 = xi + (size_t)(unsigned int)p[3] * 32 + sl;
        const f32x4* a4 = xi + (size_t)(unsigned int)p[4] * 32 + sl;
        const f32x4* a5 = xi + (size_t)(unsigned int)p[5] * 32 + sl;
        const f32x4* a6 = xi + (size_t)(unsigned int)p[6] * 32 + sl;
        const f32x4* a7 = xi + (size_t)(unsigned int)p[7] * 32 + sl;
        f32x4 x0, x1, x2, x3, x4, x5, x6, x7;
        asm volatile(
            "global_load_dwordx4 %0, %8, off\n\t"
            "global_load_dwordx4 %1, %9, off\n\t"
            "global_load_dwordx4 %2, %10, off\n\t"
            "global_load_dwordx4 %3, %11, off\n\t"
            "global_load_dwordx4 %4, %12, off\n\t"
            "global_load_dwordx4 %5, %13, off\n\t"
            "global_load_dwordx4 %6, %14, off\n\t"
            "global_load_dwordx4 %7, %15, off"
            : "=&v"(x0), "=&v"(x1), "=&v"(x2), "=&v"(x3),
              "=&v"(x4), "=&v"(x5), "=&v"(x6), "=&v"(x7)
            : "v"(a0), "v"(a1), "v"(a2), "v"(a3),
              "v"(a4), "v"(a5), "v"(a6), "v"(a7));
        asm volatile("s_waitcnt vmcnt(0)" ::: "memory");
        __builtin_amdgcn_sched_barrier(0);
        fma8(acc, __int_as_float((int)(p[0] >> 32)), x0);
        fma8(acc, __int_as_float((int)(p[1] >> 32)), x1);
        fma8(acc, __int_as_float((int)(p[2] >> 32)), x2);
        fma8(acc, __int_as_float((int)(p[3] >> 32)), x3);
        fma8(acc, __int_as_float((int)(p[4] >> 32)), x4);
        fma8(acc, __int_as_float((int)(p[5] >> 32)), x5);
        fma8(acc, __int_as_float((int)(p[6] >> 32)), x6);
        fma8(acc, __int_as_float((int)(p[7] >> 32)), x7);
    }
    // mid: 8 edges; slot s handles edges [base+4s, base+4s+4), forced 4-deep
    if (base + 8 <= e1) {
        long long p[4];
#pragma unroll
        for (int i = 0; i < 4; ++i)
            p[i] = __builtin_nontemporal_load(&epk[base + sub * 4 + i]);
        const f32x4* a0 = xi + (size_t)(unsigned int)p[0] * 32 + sl;
        const f32x4* a1 = xi + (size_t)(unsigned int)p[1] * 32 + sl;
        const f32x4* a2 = xi + (size_t)(unsigned int)p[2] * 32 + sl;
        const f32x4* a3 = xi + (size_t)(unsigned int)p[3] * 32 + sl;
        f32x4 x0, x1, x2, x3;
        asm volatile(
            "global_load_dwordx4 %0, %4, off\n\t"
            "global_load_dwordx4 %1, %5, off\n\t"
            "global_load_dwordx4 %2, %6, off\n\t"
            "global_load_dwordx4 %3, %7, off"
            : "=&v"(x0), "=&v"(x1), "=&v"(x2), "=&v"(x3)
            : "v"(a0), "v"(a1), "v"(a2), "v"(a3));
        asm volatile("s_waitcnt vmcnt(0)" ::: "memory");
        __builtin_amdgcn_sched_barrier(0);
        fma8(acc, __int_as_float((int)(p[0] >> 32)), x0);
        fma8(acc, __int_as_float((int)(p[1] >> 32)), x1);
        fma8(acc, __int_as_float((int)(p[2] >> 32)), x2);
        fma8(acc, __int_as_float((int)(p[3] >> 32)), x3);
        base += 8;
    }
    if (base < e1) {             // tail: 1..7 edges, masked, C path
#pragma unroll
        for (int i = 0; i < 4; ++i) {
            int idx = base + 2 * i + sub;
            bool valid = idx < e1;
            int idxc = valid ? idx : e0;
            long long p = epk[idxc];
            int c = (int)(unsigned int)p;
            float v = valid ? __int_as_float((int)(p >> 32)) : 0.f;
            f32x4 xv = xi[(size_t)c * 32 + sl];
            fma8(acc, v, xv);
        }
    }
    // reduce across the 2 edge slots
#pragma unroll
    for (int j = 0; j < 8; ++j) acc[j] += __shfl_xor(acc[j], 32, 64);
    if (sub == 0) {
        union { __half h[8]; f32x4 f; } u;
#pragma unroll
        for (int j = 0; j < 8; ++j) u.h[j] = __float2half_rn(acc[j]);
        __builtin_nontemporal_store(u.f, (f32x4*)&((float4*)xout)[(size_t)r * 32 + sl]);
    }
}

// ---------------- MFMA GEMM with split-fp16 precision ----------------
// AMODE 0: A fp32, split to hi/lo in-kernel (fallback if workspace too small)
// AMODE 1: A fp16 single (2 MFMA: A*Wh + A*Wl)
// AMODE 2: A pre-split fp16 hi/lo  (3 MFMA: Ah*Wh + Al*Wh + Ah*Wl)
template<int AMODE, bool TANH, typename Tout, int BN>
__global__ __launch_bounds__(256) void gemm_mfma(
    const void* __restrict__ Av, const _Float16* __restrict__ Al,
    const _Float16* __restrict__ WTh, const _Float16* __restrict__ WTl,
    const float* __restrict__ bias, Tout* __restrict__ C, int M_A, int M_C, int NC)
{
    __shared__ _Float16 As_hi[128 * LSTR];
    __shared__ _Float16 As_lo[(AMODE != 1 ? 128 : 1) * LSTR];
    __shared__ _Float16 Ws_hi[BN * LSTR];
    __shared__ _Float16 Ws_lo[BN * LSTR];

    int tid = threadIdx.x;
    int lane = tid & 63;
    int w = tid >> 6;
    int q = lane >> 4;          // quad 0..3
    int r16 = lane & 15;
    int m0 = blockIdx.x * 128;
    int n0 = blockIdx.y * BN;

    constexpr int MT = (BN == 128) ? 4 : 2;
    int wm = (BN == 128) ? (w & 1) * 64 : w * 32;
    int wn = (BN == 128) ? (w >> 1) * 64 : 0;

    f32x4 acc[MT][4];
#pragma unroll
    for (int mt = 0; mt < MT; ++mt)
#pragma unroll
        for (int nt = 0; nt < 4; ++nt) acc[mt][nt] = (f32x4){0.f, 0.f, 0.f, 0.f};

    for (int k0 = 0; k0 < 256; k0 += 32) {
        // ---- stage A tile (128 x 32) ----
        if (AMODE == 0) {
            const float* A = (const float*)Av;
#pragma unroll
            for (int p = 0; p < 4; ++p) {
                int idx = tid + p * 256;          // 1024 float4 chunks
                int m = idx >> 3, kc = idx & 7;
                int gm = m0 + m;
                float4 av = make_float4(0.f, 0.f, 0.f, 0.f);
                if (gm < M_A) av = *(const float4*)&A[(size_t)gm * 256 + k0 + kc * 4];
                half4 hi, lo;
                hi.x = (_Float16)av.x; lo.x = (_Float16)(av.x - (float)hi.x);
                hi.y = (_Float16)av.y; lo.y = (_Float16)(av.y - (float)hi.y);
                hi.z = (_Float16)av.z; lo.z = (_Float16)(av.z - (float)hi.z);
                hi.w = (_Float16)av.w; lo.w = (_Float16)(av.w - (float)hi.w);
                *(half4*)&As_hi[m * LSTR + kc * 4] = hi;
                *(half4*)&As_lo[m * LSTR + kc * 4] = lo;
            }
        } else {
            const _Float16* A = (const _Float16*)Av;
#pragma unroll
            for (int p = 0; p < 2; ++p) {
                int idx = tid + p * 256;          // 512 chunks of 8 halves
                int m = idx >> 2, kc = idx & 3;
                *(half8*)&As_hi[m * LSTR + kc * 8] =
                    *(const half8*)&A[(size_t)(m0 + m) * 256 + k0 + kc * 8];
                if (AMODE == 2)
                    *(half8*)&As_lo[m * LSTR + kc * 8] =
                        *(const half8*)&Al[(size_t)(m0 + m) * 256 + k0 + kc * 8];
            }
        }
        // ---- stage W tile (BN x 32, hi+lo) ----
#pragma unroll
        for (int p = 0; p < BN / 64; ++p) {
            int idx = tid + p * 256;
            int n = idx >> 2, kc = idx & 3;
            *(half8*)&Ws_hi[n * LSTR + kc * 8] = *(const half8*)&WTh[(size_t)(n0 + n) * 256 + k0 + kc * 8];
            *(half8*)&Ws_lo[n * LSTR + kc * 8] = *(const half8*)&WTl[(size_t)(n0 + n) * 256 + k0 + kc * 8];
        }
        __syncthreads();

        // ---- fragments ----
        half8 af_h[MT], af_l[MT], wf_h[4], wf_l[4];
#pragma unroll
        for (int mt = 0; mt < MT; ++mt) {
            int mrow = wm + mt * 16 + r16;
            af_h[mt] = *(const half8*)&As_hi[mrow * LSTR + q * 8];
            if (AMODE != 1) af_l[mt] = *(const half8*)&As_lo[mrow * LSTR + q * 8];
        }
#pragma unroll
        for (int nt = 0; nt < 4; ++nt) {
            int nrow = wn + nt * 16 + r16;
            wf_h[nt] = *(const half8*)&Ws_hi[nrow * LSTR + q * 8];
            wf_l[nt] = *(const half8*)&Ws_lo[nrow * LSTR + q * 8];
        }
        // ---- MFMA ----
#pragma unroll
        for (int mt = 0; mt < MT; ++mt)
#pragma unroll
            for (int nt = 0; nt < 4; ++nt) {
                acc[mt][nt] = mfma16(af_h[mt], wf_h[nt], acc[mt][nt]);
                if (AMODE != 1) acc[mt][nt] = mfma16(af_l[mt], wf_h[nt], acc[mt][nt]);
                acc[mt][nt] = mfma16(af_h[mt], wf_l[nt], acc[mt][nt]);
            }
        __syncthreads();
    }

    // ---- epilogue: bias (+ tanh) -> store (C layout: col=lane&15, row=quad*4+reg) ----
#pragma unroll
    for (int nt = 0; nt < 4; ++nt) {
        float b = bias[n0 + wn + nt * 16 + r16];
        int gc = n0 + wn + nt * 16 + r16;
#pragma unroll
        for (int mt = 0; mt < MT; ++mt) {
#pragma unroll
            for (int r = 0; r < 4; ++r) {
                int gm = m0 + wm + mt * 16 + q * 4 + r;
                float v = acc[mt][nt][r] + b;
                if (TANH) v = fast_tanh(v);
                if (gm < M_C) C[(size_t)gm * NC + gc] = (Tout)v;
            }
        }
    }
}

extern "C" void kernel_launch(void* const* d_in, const int* in_sizes, int n_in,
                              void* d_out, int out_size, void* d_ws, size_t ws_size,
                              hipStream_t stream) {
    const float* x      = (const float*)d_in[0];
    const int*   erows  = (const int*)d_in[1];
    const int*   ecols  = (const int*)d_in[2];
    const float* evals  = (const float*)d_in[3];
    const float* gamma  = (const float*)d_in[4];
    const float* beta   = (const float*)d_in[5];
    const float* w_in   = (const float*)d_in[6];
    const float* b_in   = (const float*)d_in[7];
    const float* w_conv = (const float*)d_in[8];
    const float* b_conv = (const float*)d_in[9];
    const float* w_out  = (const float*)d_in[10];
    const float* b_out  = (const float*)d_in[11];
    float* out = (float*)d_out;

    char* ws = (char*)d_ws;
    size_t off = 0;
    auto alloc = [&](size_t bytes) -> void* {
        void* p = ws + off;
        off = (off + bytes + 255) & ~(size_t)255;
        return p;
    };
    _Float16* h1     = (_Float16*)alloc((size_t)NNP * DD * 2);
    _Float16* h2     = (_Float16*)alloc((size_t)NNP * DD * 2);
    int2*  edgesP = (int2*) alloc((size_t)NBK * CAP * 8);
    int2*  ebufP  = (int2*) alloc((size_t)NBK * CAP * 8);
    int*   rps    = (int*)  alloc((size_t)NN * 4);
    int*   rpe    = (int*)  alloc((size_t)NN * 4);
    float* stats  = (float*)alloc(2 * DD * 4);       // 2048 B (256-aligned)
    int*   cnt    = (int*)  alloc((size_t)NBK * 4);  // contiguous after stats
    _Float16* wt1h = (_Float16*)alloc((size_t)DD * DD * 2);
    _Float16* wt1l = (_Float16*)alloc((size_t)DD * DD * 2);
    _Float16* wt2h = (_Float16*)alloc((size_t)DD * DD * 2);
    _Float16* wt2l = (_Float16*)alloc((size_t)DD * DD * 2);
    _Float16* wt3h = (_Float16*)alloc((size_t)DOUTC * DD * 2);
    _Float16* wt3l = (_Float16*)alloc((size_t)DOUTC * DD * 2);
    float* bfold = (float*)alloc(DD * 4);
    // pre-split A: xh aliases h2 (h2 is dead until spmm hop 1); xl is a fresh slab.
    _Float16* xh = h2;
    _Float16* xl = (_Float16*)alloc((size_t)NNP * DD * 2);
    bool presplit = (off <= ws_size);

    // one memset covers stats (2048 B) + cnt (NBK*4, adjacent)
    hipMemsetAsync(stats, 0, 2 * DD * 4 + (size_t)NBK * 4, stream);

    // Phase A: col_stats (+x split) || global-atomic bucket scatter
    if (presplit) {
        phaseA_kernel<true><<<STATB + PB, 256, 0, stream>>>(
            x, stats, xh, xl, erows, ecols, evals, cnt, ebufP);
    } else {
        phaseA_kernel<false><<<STATB + PB, 256, 0, stream>>>(
            x, stats, nullptr, nullptr, erows, ecols, evals, cnt, ebufP);
    }

    // Phase B: per-bucket finalize (row sort -> rps/rpe/edgesP) || weight prep
    phaseB_kernel<<<NBK + 3 * DD + 1, 256, 0, stream>>>(
        cnt, ebufP, rps, rpe, edgesP,
        stats, gamma, beta, w_in, b_in, w_conv, w_out,
        wt1h, wt1l, wt2h, wt2l, wt3h, wt3l, bfold);

    dim3 g2(NNP / 128, 2), g1(NNP / 128, 1);
    // GEMM1: pre-split fp16 A -> tanh -> fp16 h1 (fallback: fp32 A, in-kernel split)
    if (presplit) {
        gemm_mfma<2, true, _Float16, 128><<<g2, 256, 0, stream>>>(
            xh, xl, wt1h, wt1l, bfold, h1, NNP, NNP, DD);
    } else {
        gemm_mfma<0, true, _Float16, 128><<<g2, 256, 0, stream>>>(
            x, nullptr, wt1h, wt1l, bfold, h1, NN, NNP, DD);
    }

    // 4 spmm hops, single full-row pass each
    spmm_kernel<<<NN / 4, 256, 0, stream>>>(rps, rpe, edgesP, (const __half*)h1, (__half*)h2);
    spmm_kernel<<<NN / 4, 256, 0, stream>>>(rps, rpe, edgesP, (const __half*)h2, (__half*)h1);
    spmm_kernel<<<NN / 4, 256, 0, stream>>>(rps, rpe, edgesP, (const __half*)h1, (__half*)h2);
    spmm_kernel<<<NN / 4, 256, 0, stream>>>(rps, rpe, edgesP, (const __half*)h2, (__half*)h1);

    // GEMM2: fp16 A -> tanh -> fp16 h2
    gemm_mfma<1, true, _Float16, 128><<<g2, 256, 0, stream>>>(
        h1, nullptr, wt2h, wt2l, b_conv, h2, NNP, NNP, DD);
    // GEMM3: fp16 A -> fp32 logits
    gemm_mfma<1, false, float, 64><<<g1, 256, 0, stream>>>(
        h2, nullptr, wt3h, wt3l, b_out, out, NNP, NN, DOUTC);
}

// Round 6
// 1440.061 us; speedup vs baseline: 1.3911x; 1.3911x over previous
//
#include <hip/hip_runtime.h>
#include <hip/hip_fp16.h>

#define NN   100000
#define NNP  100096          // 782 * 128, padded row count for hop/GEMM buffers
#define EE   3200000
#define DD   256
#define DOUTC 64
#define LSTR 40              // LDS row stride in halves (80 B, 16B-aligned, 2-way bank alias = free)

#define NBK  782             // buckets of 128 rows (row >> 7); 782*128 = 100096 >= NN
#define PB   512             // partition blocks for count/scatter
#define CHUNK 6250           // edges per partition block; 512*6250 = EE exactly
#define STATB 512            // col_stats blocks

typedef _Float16 half8 __attribute__((ext_vector_type(8)));
typedef _Float16 half4 __attribute__((ext_vector_type(4)));
typedef float    f32x4 __attribute__((ext_vector_type(4)));

__device__ inline f32x4 mfma16(half8 a, half8 b, f32x4 c) {
    return __builtin_amdgcn_mfma_f32_16x16x32_f16(a, b, c, 0, 0, 0);
}

// fast tanh: 1 - 2/(e^{2v}+1). v_exp + v_rcp, ~1e-7 abs error (fp16 downstream).
__device__ inline float fast_tanh(float v) {
    float e = __expf(2.0f * v);
    return 1.0f - 2.0f * __builtin_amdgcn_rcpf(e + 1.0f);
}

// ========== Phase A: col_stats (blocks 0..STATB-1) || LDS-binned bucket count ==========
// stats: sum/sumsq per column (+ optional x -> hi/lo fp16 split) -> atomicAdd into stats[].
// count: per-partition-block bucket counts -> Cm[PB][NBK] (LDS bins, NO global atomics).
template<bool WSPLIT>
__global__ __launch_bounds__(256) void statsCount_kernel(
        const float* __restrict__ x, float* __restrict__ stats,
        _Float16* __restrict__ xh, _Float16* __restrict__ xl,
        const int* __restrict__ rows, int* __restrict__ Cm) {
    int blk = blockIdx.x;
    int tid = threadIdx.x;
    if (blk < STATB) {
        __shared__ float4 shs[4][64];
        __shared__ float4 shs2[4][64];
        int c4 = tid & 63;          // float4 chunk of the 256-col row
        int rq = tid >> 6;          // wave id 0..3
        float4 s  = make_float4(0.f, 0.f, 0.f, 0.f);
        float4 s2 = make_float4(0.f, 0.f, 0.f, 0.f);
        for (int r = blk * 4 + rq; r < NN; r += STATB * 4) {
            float4 v = *(const float4*)&x[(size_t)r * DD + c4 * 4];
            s.x += v.x; s.y += v.y; s.z += v.z; s.w += v.w;
            s2.x += v.x * v.x; s2.y += v.y * v.y; s2.z += v.z * v.z; s2.w += v.w * v.w;
            if (WSPLIT) {
                half4 hi, lo;
                hi.x = (_Float16)v.x; lo.x = (_Float16)(v.x - (float)hi.x);
                hi.y = (_Float16)v.y; lo.y = (_Float16)(v.y - (float)hi.y);
                hi.z = (_Float16)v.z; lo.z = (_Float16)(v.z - (float)hi.z);
                hi.w = (_Float16)v.w; lo.w = (_Float16)(v.w - (float)hi.w);
                *(half4*)&xh[(size_t)r * DD + c4 * 4] = hi;
                *(half4*)&xl[(size_t)r * DD + c4 * 4] = lo;
            }
        }
        shs[rq][c4] = s;
        shs2[rq][c4] = s2;
        __syncthreads();
        if (rq == 0) {
#pragma unroll
            for (int q = 1; q < 4; ++q) {
                float4 a = shs[q][c4], b = shs2[q][c4];
                s.x += a.x; s.y += a.y; s.z += a.z; s.w += a.w;
                s2.x += b.x; s2.y += b.y; s2.z += b.z; s2.w += b.w;
            }
            atomicAdd(&stats[c4 * 4 + 0], s.x);
            atomicAdd(&stats[c4 * 4 + 1], s.y);
            atomicAdd(&stats[c4 * 4 + 2], s.z);
            atomicAdd(&stats[c4 * 4 + 3], s.w);
            atomicAdd(&stats[DD + c4 * 4 + 0], s2.x);
            atomicAdd(&stats[DD + c4 * 4 + 1], s2.y);
            atomicAdd(&stats[DD + c4 * 4 + 2], s2.z);
            atomicAdd(&stats[DD + c4 * 4 + 3], s2.w);
        }
    } else {
        __shared__ int bins[NBK];
        int pb = blk - STATB;
        for (int i = tid; i < NBK; i += 256) bins[i] = 0;
        __syncthreads();
        int base = pb * CHUNK;
        for (int e = base + tid; e < base + CHUNK; e += 256) {
            int r = __builtin_nontemporal_load(&rows[e]);
            atomicAdd(&bins[r >> 7], 1);
        }
        __syncthreads();
        for (int i = tid; i < NBK; i += 256) Cm[(size_t)pb * NBK + i] = bins[i];
    }
}

// B1: exclusive scan down each bucket column of Cm; totals -> Tb
__global__ __launch_bounds__(256) void scan_col_kernel(int* __restrict__ Cm,
                                                       int* __restrict__ Tb) {
    __shared__ int s[256];
    int b = blockIdx.x;
    int t = threadIdx.x;
    int v0 = Cm[(size_t)(2 * t)     * NBK + b];
    int v1 = Cm[(size_t)(2 * t + 1) * NBK + b];
    int local = v0 + v1;
    s[t] = local;
    __syncthreads();
    for (int off = 1; off < 256; off <<= 1) {
        int xv = 0;
        if (t >= off) xv = s[t - off];
        __syncthreads();
        if (t >= off) s[t] += xv;
        __syncthreads();
    }
    int excl = s[t] - local;
    Cm[(size_t)(2 * t)     * NBK + b] = excl;
    Cm[(size_t)(2 * t + 1) * NBK + b] = excl + v0;
    if (t == 255) Tb[b] = s[255];
}

// B2: exclusive scan of bucket totals -> Bb[0..NBK], Bb[NBK] = EE
__global__ __launch_bounds__(256) void scan_buckets_kernel(const int* __restrict__ Tb,
                                                           int* __restrict__ Bb) {
    __shared__ int s[256];
    int t = threadIdx.x;
    int v[4]; int local = 0;
    for (int i = 0; i < 4; ++i) {
        int idx = t * 4 + i;
        v[i] = (idx < NBK) ? Tb[idx] : 0;
        local += v[i];
    }
    s[t] = local;
    __syncthreads();
    for (int off = 1; off < 256; off <<= 1) {
        int xv = 0;
        if (t >= off) xv = s[t - off];
        __syncthreads();
        if (t >= off) s[t] += xv;
        __syncthreads();
    }
    int excl = s[t] - local;
    int run = excl;
    for (int i = 0; i < 4; ++i) {
        int idx = t * 4 + i;
        if (idx < NBK) Bb[idx] = run;
        run += v[i];
    }
    if (t == 255) Bb[NBK] = EE;
}

// ========== Phase C: LDS-binned scatter (blocks 0..PB-1) || weight prep (PB..) ==========
// scatter: edges into bucket-contiguous ebuf, packed (rowlo<<17 | col, val).
// prep: b2 in [0,DD)=w1, [DD,2DD)=w2, [2DD,3DD)=w3, [3DD]=fold_bias.
__global__ __launch_bounds__(256) void scatterPrep_kernel(
        const int* __restrict__ rows, const int* __restrict__ cols,
        const float* __restrict__ vals, const int* __restrict__ Cm,
        const int* __restrict__ Bb, int2* __restrict__ ebuf,
        const float* __restrict__ stats, const float* __restrict__ gamma,
        const float* __restrict__ beta, const float* __restrict__ w_in,
        const float* __restrict__ b_in, const float* __restrict__ w_conv,
        const float* __restrict__ w_out,
        _Float16* __restrict__ wt1h, _Float16* __restrict__ wt1l,
        _Float16* __restrict__ wt2h, _Float16* __restrict__ wt2l,
        _Float16* __restrict__ wt3h, _Float16* __restrict__ wt3l,
        float* __restrict__ bfold) {
    int blk = blockIdx.x;
    int t = threadIdx.x;
    if (blk < PB) {
        __shared__ int bins[NBK];
        for (int i = t; i < NBK; i += 256) bins[i] = 0;
        __syncthreads();
        int base = blk * CHUNK;
        for (int e = base + t; e < base + CHUNK; e += 256) {
            int r = __builtin_nontemporal_load(&rows[e]);
            int c = __builtin_nontemporal_load(&cols[e]);
            float v = __builtin_nontemporal_load(&vals[e]);
            int bkt = r >> 7;
            int lr = atomicAdd(&bins[bkt], 1);
            int pos = Bb[bkt] + Cm[(size_t)blk * NBK + bkt] + lr;
            ebuf[pos] = make_int2(c | ((r & 127) << 17), __float_as_int(v));
        }
    } else {
        int b2 = blk - PB;
        if (b2 < DD) {                       // w1 (BN-scaled), col k=b2
            float mean = stats[b2] * (1.0f / NN);
            float var  = stats[DD + b2] * (1.0f / NN) - mean * mean;
            float a = gamma[b2] * rsqrtf(var + 1e-5f);
            float v = a * w_in[(size_t)b2 * DD + t];
            _Float16 hi = (_Float16)v;
            _Float16 lo = (_Float16)(v - (float)hi);
            wt1h[(size_t)t * DD + b2] = hi;
            wt1l[(size_t)t * DD + b2] = lo;
        } else if (b2 < 2 * DD) {            // w2, col k=b2-DD
            int k = b2 - DD;
            float v = w_conv[(size_t)k * DD + t];
            _Float16 hi = (_Float16)v;
            _Float16 lo = (_Float16)(v - (float)hi);
            wt2h[(size_t)t * DD + k] = hi;
            wt2l[(size_t)t * DD + k] = lo;
        } else if (b2 < 3 * DD) {            // w3, col k=b2-2DD (only DOUTC outputs)
            int k = b2 - 2 * DD;
            if (t < DOUTC) {
                float v = w_out[(size_t)k * DOUTC + t];
                _Float16 hi = (_Float16)v;
                _Float16 lo = (_Float16)(v - (float)hi);
                wt3h[(size_t)t * DD + k] = hi;
                wt3l[(size_t)t * DD + k] = lo;
            }
        } else {                             // fold_bias
            __shared__ float sb[DD];
            float mean = stats[t] * (1.0f / NN);
            float var  = stats[DD + t] * (1.0f / NN) - mean * mean;
            float a = gamma[t] * rsqrtf(var + 1e-5f);
            sb[t] = beta[t] - mean * a;
            __syncthreads();
            float acc = 0.f;
            for (int j = 0; j < DD; ++j) acc += sb[j] * w_in[j * DD + t];
            bfold[t] = b_in[t] + acc;
        }
    }
}

// D: per-bucket 128-row hist+scan in LDS -> rp + final row-major CSR edges
__global__ __launch_bounds__(256) void bucket_finalize_kernel(
        const int* __restrict__ Bb, const int2* __restrict__ ebuf,
        int* __restrict__ rp, int2* __restrict__ edges) {
    __shared__ int hist[128];
    __shared__ int excl[128];
    __shared__ int cur[128];
    __shared__ int sc[128];
    int b = blockIdx.x;
    int t = threadIdx.x;
    int e0 = Bb[b], e1 = Bb[b + 1];
    if (t < 128) { hist[t] = 0; cur[t] = 0; }
    __syncthreads();
    for (int e = e0 + t; e < e1; e += 256)
        atomicAdd(&hist[ebuf[e].x >> 17], 1);
    __syncthreads();
    if (t < 128) sc[t] = hist[t];
    __syncthreads();
    for (int off = 1; off < 128; off <<= 1) {
        int xv = 0;
        if (t < 128 && t >= off) xv = sc[t - off];
        __syncthreads();
        if (t < 128 && t >= off) sc[t] += xv;
        __syncthreads();
    }
    if (t < 128) {
        excl[t] = sc[t] - hist[t];
        int gr = b * 128 + t;
        if (gr < NN) rp[gr] = e0 + excl[t];
    }
    if (b == 0 && t == 0) rp[NN] = EE;
    __syncthreads();
    for (int e = e0 + t; e < e1; e += 256) {
        int2 d = ebuf[e];
        int rl = d.x >> 17;
        int lr = atomicAdd(&cur[rl], 1);
        edges[e0 + excl[rl] + lr] = make_int2(d.x & 0x1FFFF, d.y);
    }
}

// ---------------- spmm: inline-asm FORCED 8-deep gather pipeline ----------------
// 1 wave per row; 2 edge slots x 32 feature lanes (one float4 = 8 halves each).
__device__ inline void fma8(float (&acc)[8], float v, const f32x4& xv) {
    const __half2* hp = (const __half2*)&xv;
    float2 f0 = __half22float2(hp[0]);
    float2 f1 = __half22float2(hp[1]);
    float2 f2 = __half22float2(hp[2]);
    float2 f3 = __half22float2(hp[3]);
    acc[0] += v*f0.x; acc[1] += v*f0.y;
    acc[2] += v*f1.x; acc[3] += v*f1.y;
    acc[4] += v*f2.x; acc[5] += v*f2.y;
    acc[6] += v*f3.x; acc[7] += v*f3.y;
}

__global__ __launch_bounds__(256) void spmm_kernel(
        const int* __restrict__ rp, const int2* __restrict__ edges,
        const __half* __restrict__ xin, __half* __restrict__ xout) {
    int tid = threadIdx.x;
    int lane = tid & 63;
    int sub = lane >> 5;         // edge slot 0..1
    int sl = lane & 31;          // feature chunk (8 halves each), 32 = full row
    int r = __builtin_amdgcn_readfirstlane(blockIdx.x * 4 + (tid >> 6));
    int e0 = rp[r], e1 = rp[r + 1];
    const f32x4* xi = (const f32x4*)xin;   // 32 float4 chunks per row
    const long long* epk = (const long long*)edges;

    float acc[8] = {0.f,0.f,0.f,0.f,0.f,0.f,0.f,0.f};

    int base = e0;
    // main: 16 edges/iter; slot s handles edges [base+8s, base+8s+8).
    // The 8 gathers are emitted as one asm block -> guaranteed 8 loads in flight.
    for (; base + 16 <= e1; base += 16) {
        long long p[8];
#pragma unroll
        for (int i = 0; i < 8; ++i)
            p[i] = __builtin_nontemporal_load(&epk[base + sub * 8 + i]);
        const f32x4* a0 = xi + (size_t)(unsigned int)p[0] * 32 + sl;
        const f32x4* a1 = xi + (size_t)(unsigned int)p[1] * 32 + sl;
        const f32x4* a2 = xi + (size_t)(unsigned int)p[2] * 32 + sl;
        const f32x4* a3 = xi + (size_t)(unsigned int)p[3] * 32 + sl;
        const f32x4* a4 = xi + (size_t)(unsigned int)p[4] * 32 + sl;
        const f32x4* a5 = xi + (size_t)(unsigned int)p[5] * 32 + sl;
        const f32x4* a6 = xi + (size_t)(unsigned int)p[6] * 32 + sl;
        const f32x4* a7 = xi + (size_t)(unsigned int)p[7] * 32 + sl;
        f32x4 x0, x1, x2, x3, x4, x5, x6, x7;
        asm volatile(
            "global_load_dwordx4 %0, %8, off\n\t"
            "global_load_dwordx4 %1, %9, off\n\t"
            "global_load_dwordx4 %2, %10, off\n\t"
            "global_load_dwordx4 %3, %11, off\n\t"
            "global_load_dwordx4 %4, %12, off\n\t"
            "global_load_dwordx4 %5, %13, off\n\t"
            "global_load_dwordx4 %6, %14, off\n\t"
            "global_load_dwordx4 %7, %15, off"
            : "=&v"(x0), "=&v"(x1), "=&v"(x2), "=&v"(x3),
              "=&v"(x4), "=&v"(x5), "=&v"(x6), "=&v"(x7)
            : "v"(a0), "v"(a1), "v"(a2), "v"(a3),
              "v"(a4), "v"(a5), "v"(a6), "v"(a7));
        asm volatile("s_waitcnt vmcnt(0)" ::: "memory");
        __builtin_amdgcn_sched_barrier(0);
        fma8(acc, __int_as_float((int)(p[0] >> 32)), x0);
        fma8(acc, __int_as_float((int)(p[1] >> 32)), x1);
        fma8(acc, __int_as_float((int)(p[2] >> 32)), x2);
        fma8(acc, __int_as_float((int)(p[3] >> 32)), x3);
        fma8(acc, __int_as_float((int)(p[4] >> 32)), x4);
        fma8(acc, __int_as_float((int)(p[5] >> 32)), x5);
        fma8(acc, __int_as_float((int)(p[6] >> 32)), x6);
        fma8(acc, __int_as_float((int)(p[7] >> 32)), x7);
    }
    // mid: 8 edges; slot s handles edges [base+4s, base+4s+4), forced 4-deep
    if (base + 8 <= e1) {
        long long p[4];
#pragma unroll
        for (int i = 0; i < 4; ++i)
            p[i] = __builtin_nontemporal_load(&epk[base + sub * 4 + i]);
        const f32x4* a0 = xi + (size_t)(unsigned int)p[0] * 32 + sl;
        const f32x4* a1 = xi + (size_t)(unsigned int)p[1] * 32 + sl;
        const f32x4* a2 = xi + (size_t)(unsigned int)p[2] * 32 + sl;
        const f32x4* a3 = xi + (size_t)(unsigned int)p[3] * 32 + sl;
        f32x4 x0, x1, x2, x3;
        asm volatile(
            "global_load_dwordx4 %0, %4, off\n\t"
            "global_load_dwordx4 %1, %5, off\n\t"
            "global_load_dwordx4 %2, %6, off\n\t"
            "global_load_dwordx4 %3, %7, off"
            : "=&v"(x0), "=&v"(x1), "=&v"(x2), "=&v"(x3)
            : "v"(a0), "v"(a1), "v"(a2), "v"(a3));
        asm volatile("s_waitcnt vmcnt(0)" ::: "memory");
        __builtin_amdgcn_sched_barrier(0);
        fma8(acc, __int_as_float((int)(p[0] >> 32)), x0);
        fma8(acc, __int_as_float((int)(p[1] >> 32)), x1);
        fma8(acc, __int_as_float((int)(p[2] >> 32)), x2);
        fma8(acc, __int_as_float((int)(p[3] >> 32)), x3);
        base += 8;
    }
    if (base < e1) {             // tail: 1..7 edges, masked, C path
#pragma unroll
        for (int i = 0; i < 4; ++i) {
            int idx = base + 2 * i + sub;
            bool valid = idx < e1;
            int idxc = valid ? idx : e0;
            long long p = epk[idxc];
            int c = (int)(unsigned int)p;
            float v = valid ? __int_as_float((int)(p >> 32)) : 0.f;
            f32x4 xv = xi[(size_t)c * 32 + sl];
            fma8(acc, v, xv);
        }
    }
    // reduce across the 2 edge slots
#pragma unroll
    for (int j = 0; j < 8; ++j) acc[j] += __shfl_xor(acc[j], 32, 64);
    if (sub == 0) {
        union { __half h[8]; f32x4 f; } u;
#pragma unroll
        for (int j = 0; j < 8; ++j) u.h[j] = __float2half_rn(acc[j]);
        __builtin_nontemporal_store(u.f, (f32x4*)&((float4*)xout)[(size_t)r * 32 + sl]);
    }
}

// ---------------- MFMA GEMM with split-fp16 precision ----------------
// AMODE 0: A fp32, split to hi/lo in-kernel (fallback if workspace too small)
// AMODE 1: A fp16 single (2 MFMA: A*Wh + A*Wl)
// AMODE 2: A pre-split fp16 hi/lo  (3 MFMA: Ah*Wh + Al*Wh + Ah*Wl)
template<int AMODE, bool TANH, typename Tout, int BN>
__global__ __launch_bounds__(256) void gemm_mfma(
    const void* __restrict__ Av, const _Float16* __restrict__ Al,
    const _Float16* __restrict__ WTh, const _Float16* __restrict__ WTl,
    const float* __restrict__ bias, Tout* __restrict__ C, int M_A, int M_C, int NC)
{
    __shared__ _Float16 As_hi[128 * LSTR];
    __shared__ _Float16 As_lo[(AMODE != 1 ? 128 : 1) * LSTR];
    __shared__ _Float16 Ws_hi[BN * LSTR];
    __shared__ _Float16 Ws_lo[BN * LSTR];

    int tid = threadIdx.x;
    int lane = tid & 63;
    int w = tid >> 6;
    int q = lane >> 4;          // quad 0..3
    int r16 = lane & 15;
    int m0 = blockIdx.x * 128;
    int n0 = blockIdx.y * BN;

    constexpr int MT = (BN == 128) ? 4 : 2;
    int wm = (BN == 128) ? (w & 1) * 64 : w * 32;
    int wn = (BN == 128) ? (w >> 1) * 64 : 0;

    f32x4 acc[MT][4];
#pragma unroll
    for (int mt = 0; mt < MT; ++mt)
#pragma unroll
        for (int nt = 0; nt < 4; ++nt) acc[mt][nt] = (f32x4){0.f, 0.f, 0.f, 0.f};

    for (int k0 = 0; k0 < 256; k0 += 32) {
        // ---- stage A tile (128 x 32) ----
        if (AMODE == 0) {
            const float* A = (const float*)Av;
#pragma unroll
            for (int p = 0; p < 4; ++p) {
                int idx = tid + p * 256;          // 1024 float4 chunks
                int m = idx >> 3, kc = idx & 7;
                int gm = m0 + m;
                float4 av = make_float4(0.f, 0.f, 0.f, 0.f);
                if (gm < M_A) av = *(const float4*)&A[(size_t)gm * 256 + k0 + kc * 4];
                half4 hi, lo;
                hi.x = (_Float16)av.x; lo.x = (_Float16)(av.x - (float)hi.x);
                hi.y = (_Float16)av.y; lo.y = (_Float16)(av.y - (float)hi.y);
                hi.z = (_Float16)av.z; lo.z = (_Float16)(av.z - (float)hi.z);
                hi.w = (_Float16)av.w; lo.w = (_Float16)(av.w - (float)hi.w);
                *(half4*)&As_hi[m * LSTR + kc * 4] = hi;
                *(half4*)&As_lo[m * LSTR + kc * 4] = lo;
            }
        } else {
            const _Float16* A = (const _Float16*)Av;
#pragma unroll
            for (int p = 0; p < 2; ++p) {
                int idx = tid + p * 256;          // 512 chunks of 8 halves
                int m = idx >> 2, kc = idx & 3;
                *(half8*)&As_hi[m * LSTR + kc * 8] =
                    *(const half8*)&A[(size_t)(m0 + m) * 256 + k0 + kc * 8];
                if (AMODE == 2)
                    *(half8*)&As_lo[m * LSTR + kc * 8] =
                        *(const half8*)&Al[(size_t)(m0 + m) * 256 + k0 + kc * 8];
            }
        }
        // ---- stage W tile (BN x 32, hi+lo) ----
#pragma unroll
        for (int p = 0; p < BN / 64; ++p) {
            int idx = tid + p * 256;
            int n = idx >> 2, kc = idx & 3;
            *(half8*)&Ws_hi[n * LSTR + kc * 8] = *(const half8*)&WTh[(size_t)(n0 + n) * 256 + k0 + kc * 8];
            *(half8*)&Ws_lo[n * LSTR + kc * 8] = *(const half8*)&WTl[(size_t)(n0 + n) * 256 + k0 + kc * 8];
        }
        __syncthreads();

        // ---- fragments ----
        half8 af_h[MT], af_l[MT], wf_h[4], wf_l[4];
#pragma unroll
        for (int mt = 0; mt < MT; ++mt) {
            int mrow = wm + mt * 16 + r16;
            af_h[mt] = *(const half8*)&As_hi[mrow * LSTR + q * 8];
            if (AMODE != 1) af_l[mt] = *(const half8*)&As_lo[mrow * LSTR + q * 8];
        }
#pragma unroll
        for (int nt = 0; nt < 4; ++nt) {
            int nrow = wn + nt * 16 + r16;
            wf_h[nt] = *(const half8*)&Ws_hi[nrow * LSTR + q * 8];
            wf_l[nt] = *(const half8*)&Ws_lo[nrow * LSTR + q * 8];
        }
        // ---- MFMA ----
#pragma unroll
        for (int mt = 0; mt < MT; ++mt)
#pragma unroll
            for (int nt = 0; nt < 4; ++nt) {
                acc[mt][nt] = mfma16(af_h[mt], wf_h[nt], acc[mt][nt]);
                if (AMODE != 1) acc[mt][nt] = mfma16(af_l[mt], wf_h[nt], acc[mt][nt]);
                acc[mt][nt] = mfma16(af_h[mt], wf_l[nt], acc[mt][nt]);
            }
        __syncthreads();
    }

    // ---- epilogue: bias (+ tanh) -> store (C layout: col=lane&15, row=quad*4+reg) ----
#pragma unroll
    for (int nt = 0; nt < 4; ++nt) {
        float b = bias[n0 + wn + nt * 16 + r16];
        int gc = n0 + wn + nt * 16 + r16;
#pragma unroll
        for (int mt = 0; mt < MT; ++mt) {
#pragma unroll
            for (int r = 0; r < 4; ++r) {
                int gm = m0 + wm + mt * 16 + q * 4 + r;
                float v = acc[mt][nt][r] + b;
                if (TANH) v = fast_tanh(v);
                if (gm < M_C) C[(size_t)gm * NC + gc] = (Tout)v;
            }
        }
    }
}

extern "C" void kernel_launch(void* const* d_in, const int* in_sizes, int n_in,
                              void* d_out, int out_size, void* d_ws, size_t ws_size,
                              hipStream_t stream) {
    const float* x      = (const float*)d_in[0];
    const int*   erows  = (const int*)d_in[1];
    const int*   ecols  = (const int*)d_in[2];
    const float* evals  = (const float*)d_in[3];
    const float* gamma  = (const float*)d_in[4];
    const float* beta   = (const float*)d_in[5];
    const float* w_in   = (const float*)d_in[6];
    const float* b_in   = (const float*)d_in[7];
    const float* w_conv = (const float*)d_in[8];
    const float* b_conv = (const float*)d_in[9];
    const float* w_out  = (const float*)d_in[10];
    const float* b_out  = (const float*)d_in[11];
    float* out = (float*)d_out;

    char* ws = (char*)d_ws;
    size_t off = 0;
    auto alloc = [&](size_t bytes) -> void* {
        void* p = ws + off;
        off = (off + bytes + 255) & ~(size_t)255;
        return p;
    };
    _Float16* h1   = (_Float16*)alloc((size_t)NNP * DD * 2);
    _Float16* h2   = (_Float16*)alloc((size_t)NNP * DD * 2);
    int2*  edges = (int2*) alloc((size_t)EE * 8);
    int2*  ebuf  = (int2*) alloc((size_t)EE * 8);
    int*   Cm    = (int*)  alloc((size_t)PB * NBK * 4);
    int*   Tb    = (int*)  alloc((size_t)NBK * 4);
    int*   Bb    = (int*)  alloc((size_t)(NBK + 1) * 4);
    int*   rp    = (int*)  alloc((size_t)(NN + 1) * 4);
    float* stats = (float*)alloc(2 * DD * 4);
    _Float16* wt1h = (_Float16*)alloc((size_t)DD * DD * 2);
    _Float16* wt1l = (_Float16*)alloc((size_t)DD * DD * 2);
    _Float16* wt2h = (_Float16*)alloc((size_t)DD * DD * 2);
    _Float16* wt2l = (_Float16*)alloc((size_t)DD * DD * 2);
    _Float16* wt3h = (_Float16*)alloc((size_t)DOUTC * DD * 2);
    _Float16* wt3l = (_Float16*)alloc((size_t)DOUTC * DD * 2);
    float* bfold = (float*)alloc(DD * 4);
    // pre-split A: xh aliases h2 (h2 is dead until spmm hop 1); xl is a fresh slab.
    // Pad rows [NN,NNP) are never zeroed: garbage there flows only into pad rows of
    // h1/h2 (MFMA is row-local) and every store is guarded by gm < M_C.
    _Float16* xh = h2;
    _Float16* xl = (_Float16*)alloc((size_t)NNP * DD * 2);
    bool presplit = (off <= ws_size);

    hipMemsetAsync(stats, 0, 2 * DD * 4, stream);

    // Phase A: col_stats (+x split) || LDS-binned bucket count
    if (presplit) {
        statsCount_kernel<true><<<STATB + PB, 256, 0, stream>>>(
            x, stats, xh, xl, erows, Cm);
    } else {
        statsCount_kernel<false><<<STATB + PB, 256, 0, stream>>>(
            x, stats, nullptr, nullptr, erows, Cm);
    }
    scan_col_kernel<<<NBK, 256, 0, stream>>>(Cm, Tb);
    scan_buckets_kernel<<<1, 256, 0, stream>>>(Tb, Bb);
    // Phase C: LDS-binned scatter || weight prep (needs stats, ready after Phase A)
    scatterPrep_kernel<<<PB + 3 * DD + 1, 256, 0, stream>>>(
        erows, ecols, evals, Cm, Bb, ebuf,
        stats, gamma, beta, w_in, b_in, w_conv, w_out,
        wt1h, wt1l, wt2h, wt2l, wt3h, wt3l, bfold);
    bucket_finalize_kernel<<<NBK, 256, 0, stream>>>(Bb, ebuf, rp, edges);

    dim3 g2(NNP / 128, 2), g1(NNP / 128, 1);
    // GEMM1: pre-split fp16 A -> tanh -> fp16 h1 (fallback: fp32 A, in-kernel split)
    if (presplit) {
        gemm_mfma<2, true, _Float16, 128><<<g2, 256, 0, stream>>>(
            xh, xl, wt1h, wt1l, bfold, h1, NNP, NNP, DD);
    } else {
        gemm_mfma<0, true, _Float16, 128><<<g2, 256, 0, stream>>>(
            x, nullptr, wt1h, wt1l, bfold, h1, NN, NNP, DD);
    }

    // 4 spmm hops, single full-row pass each
    spmm_kernel<<<NN / 4, 256, 0, stream>>>(rp, edges, (const __half*)h1, (__half*)h2);
    spmm_kernel<<<NN / 4, 256, 0, stream>>>(rp, edges, (const __half*)h2, (__half*)h1);
    spmm_kernel<<<NN / 4, 256, 0, stream>>>(rp, edges, (const __half*)h1, (__half*)h2);
    spmm_kernel<<<NN / 4, 256, 0, stream>>>(rp, edges, (const __half*)h2, (__half*)h1);

    // GEMM2: fp16 A -> tanh -> fp16 h2
    gemm_mfma<1, true, _Float16, 128><<<g2, 256, 0, stream>>>(
        h1, nullptr, wt2h, wt2l, b_conv, h2, NNP, NNP, DD);
    // GEMM3: fp16 A -> fp32 logits
    gemm_mfma<1, false, float, 64><<<g1, 256, 0, stream>>>(
        h2, nullptr, wt3h, wt3l, b_out, out, NNP, NN, DOUTC);
}